// Round 4
// baseline (5920.037 us; speedup 1.0000x reference)
//
#include <hip/hip_runtime.h>
#include <hip/hip_bf16.h>
#include <math.h>

#define T_STEPS 512
#define B_SZ 256
#define I_SZ 256
#define H_SZ 1024

typedef unsigned short u16;
typedef unsigned int u32;
typedef unsigned long long u64;
typedef __bf16 bf16x8 __attribute__((ext_vector_type(8)));
typedef float f32x4 __attribute__((ext_vector_type(4)));

__device__ __forceinline__ u16 f2bf(float f) {
    union { float f; unsigned u; } v; v.f = f;
    unsigned r = v.u + 0x7fffu + ((v.u >> 16) & 1u);  // RNE
    return (u16)(r >> 16);
}

// L3-coherent (agent coherence point) 16B load: bypasses L1+L2 via sc0 sc1.
template<int OFF>
__device__ __forceinline__ bf16x8 ld_b128_sc(const u16* p) {
    bf16x8 r;
    asm volatile("global_load_dwordx4 %0, %1, off offset:%2 sc0 sc1"
                 : "=v"(r) : "v"(p), "i"(OFF));
    return r;
}

// L3-coherent 2B store: write-through to MALL, bypass L1+L2.
__device__ __forceinline__ void st_b16_sc(u16* p, unsigned v) {
    asm volatile("global_store_short %0, %1, off sc0 sc1"
                 :: "v"(p), "v"(v) : "memory");
}

// Per-wave ready-flag: plain dword store at the coherence point. NO atomic RMW
// -> no serialization at the MALL atomic unit (the previous 32-RMW/step
// single-line fetch_add is the suspected ~2-4us/step cost).
__device__ __forceinline__ void st_flag(u32* p, u32 v) {
    asm volatile("global_store_dword %0, %1, off sc0 sc1"
                 :: "v"(p), "v"(v) : "memory");
}

// Coalesced poll: 64 lanes x dwordx2 = all 128 team flags in ONE instruction.
__device__ __forceinline__ u64 ld_flags2(const u32* p) {
    u64 r;
    asm volatile("global_load_dwordx2 %0, %1, off sc0 sc1"
                 : "=v"(r) : "v"(p));
    return r;
}

__device__ __forceinline__ f32x4 mm(bf16x8 a, bf16x8 b, f32x4 c) {
    return __builtin_amdgcn_mfma_f32_16x16x32_bf16(a, b, c, 0, 0, 0);
}

// counted waitcnt + scheduling fence (rule #18)
#define WAITV(N) do { \
    asm volatile("s_waitcnt vmcnt(" #N ")" ::: "memory"); \
    __builtin_amdgcn_sched_barrier(0); \
} while (0)

#define LD_GRP(arr, B0) do { \
    arr[0] = ld_b128_sc<((B0)+0)*64>(hrow); \
    arr[1] = ld_b128_sc<((B0)+1)*64>(hrow); \
    arr[2] = ld_b128_sc<((B0)+2)*64>(hrow); \
    arr[3] = ld_b128_sc<((B0)+3)*64>(hrow); \
    arr[4] = ld_b128_sc<((B0)+4)*64>(hrow); \
    arr[5] = ld_b128_sc<((B0)+5)*64>(hrow); \
    arr[6] = ld_b128_sc<((B0)+6)*64>(hrow); \
    arr[7] = ld_b128_sc<((B0)+7)*64>(hrow); \
} while (0)

#define MM_GRP(arr, B0) do { \
    acc0 = mm(arr[0], wB[(B0)+0], acc0); \
    acc1 = mm(arr[1], wB[(B0)+1], acc1); \
    acc2 = mm(arr[2], wB[(B0)+2], acc2); \
    acc3 = mm(arr[3], wB[(B0)+3], acc3); \
    acc0 = mm(arr[4], wB[(B0)+4], acc0); \
    acc1 = mm(arr[5], wB[(B0)+5], acc1); \
    acc2 = mm(arr[6], wB[(B0)+6], acc2); \
    acc3 = mm(arr[7], wB[(B0)+7], acc3); \
} while (0)

// ---------------------------------------------------------------------------
// prep: fp32 -> bf16 conversions of weights + h0, zero per-wave flags.
// ws layout: [0,2MB) W_hh bf16 | [2MB,2.5MB) W_ih bf16 | hp0 512KB | hp1 512KB
//            | flags 4KB (8 teams x 32 slices x 4 waves x u32)
// ---------------------------------------------------------------------------
__global__ void prep_kernel(const float* __restrict__ wih, const float* __restrict__ whh,
                            const float* __restrict__ h0,
                            u16* __restrict__ whh_b, u16* __restrict__ wih_b,
                            u16* __restrict__ hp0, u32* __restrict__ flags) {
    int idx = blockIdx.x * blockDim.x + threadIdx.x;
    int stride = gridDim.x * blockDim.x;
    for (int i = idx; i < H_SZ * H_SZ; i += stride) whh_b[i] = f2bf(whh[i]);
    for (int i = idx; i < H_SZ * I_SZ; i += stride) wih_b[i] = f2bf(wih[i]);
    for (int i = idx; i < B_SZ * H_SZ; i += stride) hp0[i] = f2bf(h0[i]);
    if (idx < 8 * 32 * 4) flags[idx] = 0;
}

// ---------------------------------------------------------------------------
// Persistent RNN kernel — per-WAVE flag protocol, no __syncthreads in loop.
// Grid: 256 blocks x 256 threads (4 waves). 8 teams of 32 blocks:
//   team = blockIdx%8 -> batch rows [32*team,+32); slice = blockIdx/8 -> cols.
// Per step, per wave:
//   poll 128 team flags (1 coalesced dwordx2/lane) until all >= t
//   f2bf prefetched x -> issue 32 h loads (sc0 sc1) -> 8 x-MFMAs fill latency
//   counted vmcnt(24/16/8/0) h-MFMA pipeline -> tanh/EMA epilogue
//   4 h stores (sc0 sc1) -> wave vmcnt(0) -> lane0 stores wave flag (t+1)
//   out fp32 writes + x prefetch for t+1 (hidden under next poll window)
// Safety: wave writes h_{t+2} over h_t's buffer only after seeing all t+1
// flags; a t+1 flag implies that wave's h_t reads retired. Teams/rows disjoint.
// ---------------------------------------------------------------------------
__global__ void __launch_bounds__(256, 1)
rnn_persistent(const float* __restrict__ x, const float* __restrict__ h0,
               const float* __restrict__ bias,
               const u16* __restrict__ whh_b, const u16* __restrict__ wih_b,
               u16* __restrict__ hp0, u16* __restrict__ hp1,
               u32* __restrict__ flags, float* __restrict__ out)
{
    const int tid  = threadIdx.x;
    const int wid  = tid >> 6;
    const int lane = tid & 63;
    const int l16  = lane & 15;
    const int quad = lane >> 4;

    const int team  = blockIdx.x & 7;
    const int slice = blockIdx.x >> 3;

    const int row_base = team * 32 + (wid & 1) * 16;         // wave's 16 batch rows
    const int gcol     = slice * 32 + (wid >> 1) * 16 + l16; // lane's hidden col
    const int am       = row_base + l16;                     // lane's A-frag row
    const int kq       = quad * 8;                           // lane's k base

    // Pin W_hh / W_ih B-fragments in registers (persistent across all 512 steps)
    bf16x8 wB[32];
#pragma unroll
    for (int kk = 0; kk < 32; ++kk)
        wB[kk] = *reinterpret_cast<const bf16x8*>(whh_b + gcol * H_SZ + kk * 32 + kq);
    bf16x8 wI[8];
#pragma unroll
    for (int kx = 0; kx < 8; ++kx)
        wI[kx] = *reinterpret_cast<const bf16x8*>(wih_b + gcol * I_SZ + kx * 32 + kq);

    const float bias_v = bias[gcol];

    float hown[4];
#pragma unroll
    for (int i = 0; i < 4; ++i)
        hown[i] = h0[(row_base + quad * 4 + i) * H_SZ + gcol];

    // flag pointers: [team][slice][wave] u32; poller covers its team's 128
    const u32* fl_poll = flags + team * 128 + lane * 2;
    u32*       fl_mine = flags + team * 128 + slice * 4 + wid;

    // x prefetch registers (fp32, converted to bf16 at consume time)
    f32x4 xr[16];
    {
        const float* x0row = x + am * I_SZ + kq;   // t = 0
#pragma unroll
        for (int kx = 0; kx < 8; ++kx) {
            xr[2 * kx]     = *reinterpret_cast<const f32x4*>(x0row + kx * 32);
            xr[2 * kx + 1] = *reinterpret_cast<const f32x4*>(x0row + kx * 32 + 4);
        }
    }

    for (int t = 0; t < T_STEPS; ++t) {
        const u16* hcur = (t & 1) ? hp1 : hp0;
        u16*       hnxt = (t & 1) ? hp0 : hp1;

        // ---- wait for team's h_t flags (per-wave; also drains the previous
        //      iteration's out-stores and x-prefetch via the in-order vmcnt) ----
        if (t > 0) {
            const u32 tgt = (u32)t;
            for (;;) {
                u64 fv = ld_flags2(fl_poll);
                asm volatile("s_waitcnt vmcnt(0)" : "+v"(fv) :: "memory");
                __builtin_amdgcn_sched_barrier(0);
                bool ok = ((u32)fv >= tgt) && ((u32)(fv >> 32) >= tgt);
                if (__ballot(ok) == ~0ull) break;
            }
            __builtin_amdgcn_sched_barrier(0);
        }

        // ---- f2bf of prefetched x (before h-load issue so the compiler's
        //      x-wait cannot drain our counted h loads) ----
        bf16x8 ax[8];
#pragma unroll
        for (int kx = 0; kx < 8; ++kx) {
            union { u16 u[8]; bf16x8 v; } c;
#pragma unroll
            for (int j = 0; j < 4; ++j) {
                c.u[j]     = f2bf(xr[2 * kx][j]);
                c.u[4 + j] = f2bf(xr[2 * kx + 1][j]);
            }
            ax[kx] = c.v;
        }

        // ---- issue all 32 h loads (only VMEM in flight now) ----
        const u16* hrow = hcur + am * H_SZ + kq;
        bf16x8 g0[8], g1[8], g2[8], g3[8];
        LD_GRP(g0, 0);
        LD_GRP(g1, 8);
        LD_GRP(g2, 16);
        LD_GRP(g3, 24);

        // ---- x MFMAs fill the h-load L3 latency (register-only) ----
        f32x4 acc0 = {0.f,0.f,0.f,0.f}, acc1 = {0.f,0.f,0.f,0.f};
        f32x4 acc2 = {0.f,0.f,0.f,0.f}, acc3 = {0.f,0.f,0.f,0.f};
#pragma unroll
        for (int kx = 0; kx < 8; ++kx) {
            if ((kx & 3) == 0)      acc0 = mm(ax[kx], wI[kx], acc0);
            else if ((kx & 3) == 1) acc1 = mm(ax[kx], wI[kx], acc1);
            else if ((kx & 3) == 2) acc2 = mm(ax[kx], wI[kx], acc2);
            else                    acc3 = mm(ax[kx], wI[kx], acc3);
        }

        WAITV(24); MM_GRP(g0, 0);
        WAITV(16); MM_GRP(g1, 8);
        WAITV(8);  MM_GRP(g2, 16);
        WAITV(0);  MM_GRP(g3, 24);

        // ---- epilogue: bias, tanh, EMA (fp32 master state) ----
        float hn[4];
#pragma unroll
        for (int i = 0; i < 4; ++i) {
            float pre = (acc0[i] + acc1[i]) + (acc2[i] + acc3[i]) + bias_v;
            hn[i] = 0.9f * hown[i] + 0.1f * tanhf(pre);
            hown[i] = hn[i];
        }

        // ---- publish bf16 h_{t+1} to L3; wave-local release; per-wave flag ----
#pragma unroll
        for (int i = 0; i < 4; ++i)
            st_b16_sc(hnxt + (row_base + quad * 4 + i) * H_SZ + gcol,
                      (unsigned)f2bf(hn[i]));
        asm volatile("s_waitcnt vmcnt(0)" ::: "memory");   // this wave's 4 stores acked
        __builtin_amdgcn_sched_barrier(0);
        if (lane == 0) st_flag(fl_mine, (u32)(t + 1));

        // ---- fp32 outputs (after signal: off the critical path) ----
        float* orow = out + (size_t)t * (B_SZ * H_SZ);
#pragma unroll
        for (int i = 0; i < 4; ++i)
            orow[(row_base + quad * 4 + i) * H_SZ + gcol] = hn[i];

        if (t == T_STEPS - 1) {
            float* hl = out + (size_t)T_STEPS * (B_SZ * H_SZ);
#pragma unroll
            for (int i = 0; i < 4; ++i)
                hl[(row_base + quad * 4 + i) * H_SZ + gcol] = hn[i];
        }

        // ---- prefetch x_{t+1}: latency hides under the next poll window ----
        if (t + 1 < T_STEPS) {
            const float* xnrow = x + (size_t)(t + 1) * (B_SZ * I_SZ) + am * I_SZ + kq;
#pragma unroll
            for (int kx = 0; kx < 8; ++kx) {
                xr[2 * kx]     = *reinterpret_cast<const f32x4*>(xnrow + kx * 32);
                xr[2 * kx + 1] = *reinterpret_cast<const f32x4*>(xnrow + kx * 32 + 4);
            }
        }
    }
}

extern "C" void kernel_launch(void* const* d_in, const int* in_sizes, int n_in,
                              void* d_out, int out_size, void* d_ws, size_t ws_size,
                              hipStream_t stream) {
    const float* x    = (const float*)d_in[0];  // [T,B,I]
    const float* h0   = (const float*)d_in[1];  // [1,B,H]
    const float* wih  = (const float*)d_in[2];  // [H,I]
    const float* whh  = (const float*)d_in[3];  // [H,H]
    const float* bias = (const float*)d_in[4];  // [H]
    float* out = (float*)d_out;                 // [T,B,H] ++ [B,H]

    char* ws = (char*)d_ws;
    u16* whh_b = (u16*)(ws);                                   // 2 MB
    u16* wih_b = (u16*)(ws + (size_t)(2u << 20));              // 512 KB
    u16* hp0   = (u16*)(ws + (size_t)(2u << 20) + (1u << 19)); // 512 KB
    u16* hp1   = (u16*)(ws + (size_t)(2u << 20) + (2u << 19)); // 512 KB
    u32* flags = (u32*)(ws + (size_t)(2u << 20) + (3u << 19)); // 4 KB

    prep_kernel<<<dim3(1024), dim3(256), 0, stream>>>(wih, whh, h0, whh_b, wih_b, hp0, flags);
    rnn_persistent<<<dim3(256), dim3(256), 0, stream>>>(x, h0, bias, whh_b, wih_b, hp0, hp1, flags, out);
}